// Round 3
// baseline (276.111 us; speedup 1.0000x reference)
//
#include <hip/hip_runtime.h>
#include <cstdint>
#include <cstddef>

#define B_  4
#define S_  4096
#define H_  1024
#define NH_ 16
#define M_  (B_*S_)   // 16384 rows

typedef __bf16 bf16x8 __attribute__((ext_vector_type(8)));
typedef float  f32x4  __attribute__((ext_vector_type(4)));

__device__ __forceinline__ unsigned short f2b(float f) {
  union { float f; unsigned u; } v; v.f = f;
  unsigned r = v.u + 0x7FFFu + ((v.u >> 16) & 1u);
  return (unsigned short)(r >> 16);
}
__device__ __forceinline__ float b2f(unsigned short u) {
  union { unsigned u; float f; } v; v.u = ((unsigned)u) << 16;
  return v.f;
}

#define GLD16(g, l) __builtin_amdgcn_global_load_lds( \
    (const __attribute__((address_space(1))) void*)(g), \
    (__attribute__((address_space(3))) void*)(l), 16, 0, 0)

#define VM0()  asm volatile("s_waitcnt vmcnt(0)" ::: "memory")
#define BAR()  do { asm volatile("" ::: "memory"); __builtin_amdgcn_s_barrier(); \
                    asm volatile("" ::: "memory"); } while (0)

// ---------------------------------------------------------------- casts
__global__ void cast_f32_bf16(const float* __restrict__ src,
                              unsigned short* __restrict__ dst, int n4) {
  int i = blockIdx.x * blockDim.x + threadIdx.x;
  if (i >= n4) return;
  float4 f = reinterpret_cast<const float4*>(src)[i];
  ushort4 o;
  o.x = f2b(f.x); o.y = f2b(f.y); o.z = f2b(f.z); o.w = f2b(f.w);
  reinterpret_cast<ushort4*>(dst)[i] = o;
}

// 4 weights (1M elems each) -> one concatenated bf16 buffer [4][1024][1024]
__global__ void cast_w4(const float* __restrict__ w0, const float* __restrict__ w1,
                        const float* __restrict__ w2, const float* __restrict__ w3,
                        unsigned short* __restrict__ dst) {
  int i = blockIdx.x * blockDim.x + threadIdx.x;      // float4 index, 1M total
  int w = i >> 18, j = i & 0x3FFFF;
  const float* src = (w == 0) ? w0 : (w == 1) ? w1 : (w == 2) ? w2 : w3;
  float4 f = reinterpret_cast<const float4*>(src)[j];
  ushort4 o;
  o.x = f2b(f.x); o.y = f2b(f.y); o.z = f2b(f.z); o.w = f2b(f.w);
  reinterpret_cast<ushort4*>(dst)[i] = o;
}

// ---------------------------------------------------------------- 256x256 GEMM
// C[M,N] = A[M,1024] * Bt[N,1024]^T, BK=64, 512 thr = 8 waves (2M x 4N).
// Quadrant phases ordered (0,0)->(0,1)->(1,1)->(1,0): each phase reloads only
// the changed operand (A: 8 reads, B: 4 reads). Two barriers per phase.
// Stages into buf^1 spread p1:A0+B0, p2:B1, p3:A1; single vmcnt(0) drain at p4.
// LDS swizzle: 16B-chunk index ^= (row & 7) on both stage-source and reads.
// MODE 0: N=3072, bf16 out routed to Q/K/V with ELU on Q,K.
// MODE 1: N=1024, Bt is per-batch [4][1024][1024], f32 out.
template<int MODE>
__global__ __launch_bounds__(512, 2) void gemm256(
    const unsigned short* __restrict__ A_,
    const unsigned short* __restrict__ Bt_,
    void* __restrict__ out) {
  __shared__ __align__(16) unsigned short LDS[2][2][16384];  // [dbuf][A|B][256*64]

  const int NTN = (MODE == 0) ? 12 : 4;
  const int nx  = gridDim.x >> 3;
  const int b2  = (blockIdx.x & 7) * nx + (blockIdx.x >> 3);  // XCD swizzle (grid%8==0)
  const int tileM = (b2 / NTN) << 8;
  const int tileN = (b2 % NTN) << 8;

  const unsigned short* Bt_e =
      (MODE == 1) ? (Bt_ + ((size_t)(tileM >> 12) << 20)) : Bt_;

  const int tid  = threadIdx.x;
  const int lane = tid & 63, wv = tid >> 6;
  const int wmi  = wv >> 2;     // 0..1
  const int wni  = wv & 3;      // 0..3
  const int fr   = lane & 15, fq = lane >> 4;

  // staging source (pre-swizzled): instr i in {0,1}: chunk c = i*512 + tid
  const int sr0 = tid >> 3,          sc0 = (tid & 7) ^ (sr0 & 7);
  const int sr1 = (tid + 512) >> 3,  sc1 = (tid & 7) ^ (sr1 & 7);

#define STG(NB, ARR, HM, SRC, RB, TT) do {                                      \
    GLD16((SRC) + (size_t)((RB) + (HM)*128 + sr0) * 1024 + (TT)*64 + sc0*8,     \
          &LDS[NB][ARR][(HM)*8192 + wv*512]);                                   \
    GLD16((SRC) + (size_t)((RB) + (HM)*128 + sr1) * 1024 + (TT)*64 + sc1*8,     \
          &LDS[NB][ARR][(HM)*8192 + 4096 + wv*512]);                            \
  } while (0)

#define LOADA(CB, MQ) do {                                                      \
    _Pragma("unroll")                                                           \
    for (int m = 0; m < 4; m++) {                                               \
      int r = (MQ)*128 + wmi*64 + m*16 + fr;                                    \
      af[m][0] = *(const bf16x8*)&LDS[CB][0][r*64 + ((fq    ) ^ (r&7))*8];      \
      af[m][1] = *(const bf16x8*)&LDS[CB][0][r*64 + ((4 + fq) ^ (r&7))*8];      \
    }                                                                           \
  } while (0)

#define LOADB(CB, NQ) do {                                                      \
    _Pragma("unroll")                                                           \
    for (int n = 0; n < 2; n++) {                                               \
      int r = (NQ)*128 + wni*32 + n*16 + fr;                                    \
      bv[n][0] = *(const bf16x8*)&LDS[CB][1][r*64 + ((fq    ) ^ (r&7))*8];      \
      bv[n][1] = *(const bf16x8*)&LDS[CB][1][r*64 + ((4 + fq) ^ (r&7))*8];      \
    }                                                                           \
  } while (0)

#define MM(MQ, NQ) do {                                                         \
    __builtin_amdgcn_s_setprio(1);                                              \
    _Pragma("unroll")                                                           \
    for (int m = 0; m < 4; m++)                                                 \
      _Pragma("unroll")                                                         \
      for (int n = 0; n < 2; n++) {                                             \
        acc[MQ][NQ][m][n] = __builtin_amdgcn_mfma_f32_16x16x32_bf16(            \
            af[m][0], bv[n][0], acc[MQ][NQ][m][n], 0, 0, 0);                    \
        acc[MQ][NQ][m][n] = __builtin_amdgcn_mfma_f32_16x16x32_bf16(            \
            af[m][1], bv[n][1], acc[MQ][NQ][m][n], 0, 0, 0);                    \
      }                                                                         \
    __builtin_amdgcn_s_setprio(0);                                              \
  } while (0)

  f32x4 zero = {0.f, 0.f, 0.f, 0.f};
  f32x4 acc[2][2][4][2];
#pragma unroll
  for (int a = 0; a < 2; a++)
#pragma unroll
    for (int b = 0; b < 2; b++)
#pragma unroll
      for (int m = 0; m < 4; m++)
#pragma unroll
        for (int n = 0; n < 2; n++) acc[a][b][m][n] = zero;

  bf16x8 af[4][2], bv[2][2];

  // prologue: tile 0 fully into buf 0
  STG(0, 0, 0, A_,   tileM, 0);
  STG(0, 0, 1, A_,   tileM, 0);
  STG(0, 1, 0, Bt_e, tileN, 0);
  STG(0, 1, 1, Bt_e, tileN, 0);
  VM0();
  BAR();

  int cb = 0;
  for (int t = 0; t < 15; ++t) {
    const int nb = cb ^ 1;
    // P1 (0,0)
    LOADA(cb, 0); LOADB(cb, 0);
    STG(nb, 0, 0, A_,   tileM, t + 1);
    STG(nb, 1, 0, Bt_e, tileN, t + 1);
    BAR(); MM(0, 0); BAR();
    // P2 (0,1)
    LOADB(cb, 1);
    STG(nb, 1, 1, Bt_e, tileN, t + 1);
    BAR(); MM(0, 1); BAR();
    // P3 (1,1)
    LOADA(cb, 1);
    STG(nb, 0, 1, A_,   tileM, t + 1);
    BAR(); MM(1, 1); BAR();
    // P4 (1,0)
    LOADB(cb, 0);
    VM0();
    BAR(); MM(1, 0); BAR();
    cb = nb;
  }
  // last tile: no staging, no waits
  LOADA(cb, 0); LOADB(cb, 0);
  BAR(); MM(0, 0); BAR();
  LOADB(cb, 1);
  BAR(); MM(0, 1); BAR();
  LOADA(cb, 1);
  BAR(); MM(1, 1); BAR();
  LOADB(cb, 0);
  BAR(); MM(1, 0);

  // epilogue
#pragma unroll
  for (int mq = 0; mq < 2; mq++)
#pragma unroll
    for (int nq = 0; nq < 2; nq++)
#pragma unroll
      for (int m = 0; m < 4; m++)
#pragma unroll
        for (int n = 0; n < 2; n++)
#pragma unroll
          for (int r = 0; r < 4; r++) {
            int row = tileM + mq * 128 + wmi * 64 + m * 16 + fq * 4 + r;
            int col = tileN + nq * 128 + wni * 32 + n * 16 + fr;
            float v = acc[mq][nq][m][n][r];
            if (MODE == 0) {
              int reg = col >> 10, lc = col & 1023;
              if (reg < 2) v = v > 0.f ? v : (expf(v) - 1.f);   // ELU on Q,K
              ((unsigned short*)out)[(size_t)reg * ((size_t)M_ * H_) +
                                     (size_t)row * H_ + lc] = f2b(v);
            } else {
              ((float*)out)[(size_t)row * H_ + col] = v;
            }
          }
#undef MM
#undef LOADB
#undef LOADA
#undef STG
}

// ---------------------------------------------------------------- stage 2: KV partials
// kvp[bh*16+ch][d][e] = sum_{s in 256-chunk} K[b,s,h,d] * V[b,s,h,e]
__global__ __launch_bounds__(256) void kv_partial(
    const unsigned short* __restrict__ Kb,
    const unsigned short* __restrict__ Vb,
    float* __restrict__ kvp) {
  __shared__ __align__(16) unsigned short kt[32 * 64];
  __shared__ __align__(16) unsigned short vt[32 * 64];
  const int bh = blockIdx.x >> 4;
  const int ch = blockIdx.x & 15;
  const int b  = bh >> 4, h = bh & 15;
  const int t  = threadIdx.x;
  const int rr = t >> 3;
  const int cc = (t & 7) * 8;
  const int d0 = (t >> 4) * 4;
  const int e0 = (t & 15) * 4;

  float acc[4][4] = {};
  for (int s0 = ch * 256; s0 < ch * 256 + 256; s0 += 32) {
    size_t g = (size_t)(b * S_ + s0 + rr) * H_ + h * 64 + cc;
    *reinterpret_cast<uint4*>(&kt[rr * 64 + cc]) = *reinterpret_cast<const uint4*>(Kb + g);
    *reinterpret_cast<uint4*>(&vt[rr * 64 + cc]) = *reinterpret_cast<const uint4*>(Vb + g);
    __syncthreads();
#pragma unroll 4
    for (int ss = 0; ss < 32; ss++) {
      ushort4 k4 = *reinterpret_cast<const ushort4*>(&kt[ss * 64 + d0]);
      ushort4 v4 = *reinterpret_cast<const ushort4*>(&vt[ss * 64 + e0]);
      float kf[4] = {b2f(k4.x), b2f(k4.y), b2f(k4.z), b2f(k4.w)};
      float vf[4] = {b2f(v4.x), b2f(v4.y), b2f(v4.z), b2f(v4.w)};
#pragma unroll
      for (int i = 0; i < 4; i++)
#pragma unroll
        for (int j = 0; j < 4; j++) acc[i][j] += kf[i] * vf[j];
    }
    __syncthreads();
  }
  float* outp = kvp + (size_t)blockIdx.x * 4096;
#pragma unroll
  for (int i = 0; i < 4; i++)
#pragma unroll
    for (int j = 0; j < 4; j++) outp[(d0 + i) * 64 + e0 + j] = acc[i][j];
}

// reduce 16 partials -> KV[bh][d][e] bf16 (row-major d)
__global__ __launch_bounds__(256) void kv_reduce(
    const float* __restrict__ kvp, unsigned short* __restrict__ KVb) {
  const int bh = blockIdx.x;
#pragma unroll
  for (int i = 0; i < 16; i++) {
    int idx = threadIdx.x + i * 256;
    float s = 0.f;
#pragma unroll
    for (int ch = 0; ch < 16; ch++) s += kvp[(size_t)(bh * 16 + ch) * 4096 + idx];
    KVb[(size_t)bh * 4096 + idx] = f2b(s);
  }
}

// ---------------------------------------------------------------- merged weight
// MbT[b][n][h*64+d] = sum_e KV[b,h][d][e] * Wo[n][h*64+e]   (Bt layout for final GEMM)
__global__ __launch_bounds__(256) void merge_m(
    const unsigned short* __restrict__ KVb,
    const unsigned short* __restrict__ Wob,
    unsigned short* __restrict__ MbT) {
  const int bh = blockIdx.x >> 2;
  const int nc = blockIdx.x & 3;
  const int b  = bh >> 4, h = bh & 15;
  const int lane = threadIdx.x & 63, wv = threadIdx.x >> 6;
  const int fr = lane & 15, fq = lane >> 4;
  const int ncb = nc * 256 + wv * 64;

  f32x4 zero = {0.f, 0.f, 0.f, 0.f};
  f32x4 acc[4][4];
#pragma unroll
  for (int i = 0; i < 4; i++)
#pragma unroll
    for (int j = 0; j < 4; j++) acc[i][j] = zero;

#pragma unroll
  for (int kk = 0; kk < 2; kk++) {
    bf16x8 af[4], bvv[4];
#pragma unroll
    for (int i = 0; i < 4; i++)
      af[i] = *(const bf16x8*)&KVb[(size_t)bh * 4096 + (i * 16 + fr) * 64 + kk * 32 + fq * 8];
#pragma unroll
    for (int j = 0; j < 4; j++)
      bvv[j] = *(const bf16x8*)&Wob[(size_t)(ncb + j * 16 + fr) * 1024 + h * 64 + kk * 32 + fq * 8];
#pragma unroll
    for (int i = 0; i < 4; i++)
#pragma unroll
      for (int j = 0; j < 4; j++)
        acc[i][j] = __builtin_amdgcn_mfma_f32_16x16x32_bf16(af[i], bvv[j], acc[i][j], 0, 0, 0);
  }
#pragma unroll
  for (int i = 0; i < 4; i++)
#pragma unroll
    for (int j = 0; j < 4; j++)
#pragma unroll
      for (int r = 0; r < 4; r++) {
        int n = ncb + j * 16 + fr;
        int k = h * 64 + i * 16 + fq * 4 + r;
        MbT[((size_t)b << 20) + (size_t)n * 1024 + k] = f2b(acc[i][j][r]);
      }
}

// ---------------------------------------------------------------- launch
extern "C" void kernel_launch(void* const* d_in, const int* in_sizes, int n_in,
                              void* d_out, int out_size, void* d_ws, size_t ws_size,
                              hipStream_t stream) {
  (void)in_sizes; (void)n_in; (void)out_size; (void)ws_size;
  const float* X  = (const float*)d_in[0];
  const float* Wq = (const float*)d_in[1];
  const float* Wk = (const float*)d_in[2];
  const float* Wv = (const float*)d_in[3];
  const float* Wo = (const float*)d_in[4];

  char*  ws  = (char*)d_ws;
  size_t off = 0;
  auto alloc = [&](size_t bytes) -> char* {
    char* p = ws + off;
    off += (bytes + 255) & ~(size_t)255;
    return p;
  };
  unsigned short* Xb   = (unsigned short*)alloc((size_t)M_ * H_ * 2);
  unsigned short* Wcat = (unsigned short*)alloc((size_t)4 * H_ * H_ * 2);  // Wq|Wk|Wv|Wo
  unsigned short* QKVb = (unsigned short*)alloc((size_t)3 * M_ * H_ * 2);  // Q|K|V
  float*          kvp  = (float*)alloc((size_t)64 * 16 * 4096 * 4);
  unsigned short* KVb  = (unsigned short*)alloc((size_t)64 * 4096 * 2);
  unsigned short* MbT  = (unsigned short*)alloc((size_t)4 * H_ * H_ * 2);

  unsigned short* Qb = QKVb;
  unsigned short* Kb = QKVb + (size_t)M_ * H_;
  unsigned short* Vb = QKVb + (size_t)2 * M_ * H_;
  unsigned short* Wob = Wcat + (size_t)3 * H_ * H_;

  cast_f32_bf16<<<(M_ * H_) / 1024, 256, 0, stream>>>(X, Xb, (M_ * H_) / 4);
  cast_w4<<<(4 * H_ * H_) / 1024, 256, 0, stream>>>(Wq, Wk, Wv, Wo, Wcat);

  gemm256<0><<<768, 512, 0, stream>>>(Xb, Wcat, QKVb);   // Q,K,V (ELU on Q,K)

  kv_partial<<<1024, 256, 0, stream>>>(Kb, Vb, kvp);
  kv_reduce<<<64, 256, 0, stream>>>(kvp, KVb);
  merge_m<<<256, 256, 0, stream>>>(KVb, Wob, MbT);

  gemm256<1><<<256, 512, 0, stream>>>(Qb, MbT, (float*)d_out);  // Y = Q @ M[b]^T
}

// Round 4
// 271.693 us; speedup vs baseline: 1.0163x; 1.0163x over previous
//
#include <hip/hip_runtime.h>
#include <cstdint>
#include <cstddef>

#define B_  4
#define S_  4096
#define H_  1024
#define NH_ 16
#define M_  (B_*S_)   // 16384 rows

typedef __bf16 bf16x8 __attribute__((ext_vector_type(8)));
typedef float  f32x4  __attribute__((ext_vector_type(4)));

__device__ __forceinline__ unsigned short f2b(float f) {
  union { float f; unsigned u; } v; v.f = f;
  unsigned r = v.u + 0x7FFFu + ((v.u >> 16) & 1u);
  return (unsigned short)(r >> 16);
}
__device__ __forceinline__ float b2f(unsigned short u) {
  union { unsigned u; float f; } v; v.u = ((unsigned)u) << 16;
  return v.f;
}

#define GLD16(g, l) __builtin_amdgcn_global_load_lds( \
    (const __attribute__((address_space(1))) void*)(g), \
    (__attribute__((address_space(3))) void*)(l), 16, 0, 0)

#define VM0()  asm volatile("s_waitcnt vmcnt(0)" ::: "memory")
#define BAR()  do { asm volatile("" ::: "memory"); __builtin_amdgcn_s_barrier(); \
                    asm volatile("" ::: "memory"); } while (0)

// ---------------------------------------------------------------- casts
__global__ void cast_f32_bf16(const float* __restrict__ src,
                              unsigned short* __restrict__ dst, int n4) {
  int i = blockIdx.x * blockDim.x + threadIdx.x;
  if (i >= n4) return;
  float4 f = reinterpret_cast<const float4*>(src)[i];
  ushort4 o;
  o.x = f2b(f.x); o.y = f2b(f.y); o.z = f2b(f.z); o.w = f2b(f.w);
  reinterpret_cast<ushort4*>(dst)[i] = o;
}

// 4 weights (1M elems each) -> one concatenated bf16 buffer [4][1024][1024]
__global__ void cast_w4(const float* __restrict__ w0, const float* __restrict__ w1,
                        const float* __restrict__ w2, const float* __restrict__ w3,
                        unsigned short* __restrict__ dst) {
  int i = blockIdx.x * blockDim.x + threadIdx.x;      // float4 index, 1M total
  int w = i >> 18, j = i & 0x3FFFF;
  const float* src = (w == 0) ? w0 : (w == 1) ? w1 : (w == 2) ? w2 : w3;
  float4 f = reinterpret_cast<const float4*>(src)[j];
  ushort4 o;
  o.x = f2b(f.x); o.y = f2b(f.y); o.z = f2b(f.z); o.w = f2b(f.w);
  reinterpret_cast<ushort4*>(dst)[i] = o;
}

// ---------------------------------------------------------------- 256x256 GEMM
// C[M,N] = A[M,1024] * Bt[N,1024]^T, BK=64, 512 thr = 8 waves (2M x 4N).
// Quadrant phases (0,0)->(0,1)->(1,1)->(1,0); each reloads only the changed
// operand. All 8 stage loads (tile t+1 -> buf^1) issued in P1; one vmcnt(0)
// drain at P4 (~3 phases of slack >> L2 latency). 2 barriers per phase.
// LDS swizzle: 16B-chunk index ^= (row & 7) on both stage-source and reads.
// Epilogue: regs -> XOR-swizzled LDS -> b128 readback -> coalesced dwordx4.
// MODE 0: N=3072, bf16 out routed to Q/K/V with ELU on Q,K.
// MODE 1: N=1024, Bt is per-batch [4][1024][1024], f32 out.
template<int MODE>
__global__ __launch_bounds__(512, 2) void gemm256(
    const unsigned short* __restrict__ A_,
    const unsigned short* __restrict__ Bt_,
    void* __restrict__ out) {
  __shared__ __align__(16) unsigned short LDS[2][2][16384];  // [dbuf][A|B][256*64]

  const int NTN = (MODE == 0) ? 12 : 4;
  const int nx  = gridDim.x >> 3;
  const int b2  = (blockIdx.x & 7) * nx + (blockIdx.x >> 3);  // XCD swizzle (grid%8==0)
  const int tileM = (b2 / NTN) << 8;
  const int tileN = (b2 % NTN) << 8;

  const unsigned short* Bt_e =
      (MODE == 1) ? (Bt_ + ((size_t)(tileM >> 12) << 20)) : Bt_;

  const int tid  = threadIdx.x;
  const int lane = tid & 63, wv = tid >> 6;
  const int wmi  = wv >> 2;     // 0..1
  const int wni  = wv & 3;      // 0..3
  const int fr   = lane & 15, fq = lane >> 4;

  // staging source (pre-swizzled): instr i in {0,1}: chunk c = i*512 + tid
  const int sr0 = tid >> 3,          sc0 = (tid & 7) ^ (sr0 & 7);
  const int sr1 = (tid + 512) >> 3,  sc1 = (tid & 7) ^ (sr1 & 7);

#define STG(NB, ARR, HM, SRC, RB, TT) do {                                      \
    GLD16((SRC) + (size_t)((RB) + (HM)*128 + sr0) * 1024 + (TT)*64 + sc0*8,     \
          &LDS[NB][ARR][(HM)*8192 + wv*512]);                                   \
    GLD16((SRC) + (size_t)((RB) + (HM)*128 + sr1) * 1024 + (TT)*64 + sc1*8,     \
          &LDS[NB][ARR][(HM)*8192 + 4096 + wv*512]);                            \
  } while (0)

#define LOADA(CB, MQ) do {                                                      \
    _Pragma("unroll")                                                           \
    for (int m = 0; m < 4; m++) {                                               \
      int r = (MQ)*128 + wmi*64 + m*16 + fr;                                    \
      af[m][0] = *(const bf16x8*)&LDS[CB][0][r*64 + ((fq    ) ^ (r&7))*8];      \
      af[m][1] = *(const bf16x8*)&LDS[CB][0][r*64 + ((4 + fq) ^ (r&7))*8];      \
    }                                                                           \
  } while (0)

#define LOADB(CB, NQ) do {                                                      \
    _Pragma("unroll")                                                           \
    for (int n = 0; n < 2; n++) {                                               \
      int r = (NQ)*128 + wni*32 + n*16 + fr;                                    \
      bv[n][0] = *(const bf16x8*)&LDS[CB][1][r*64 + ((fq    ) ^ (r&7))*8];      \
      bv[n][1] = *(const bf16x8*)&LDS[CB][1][r*64 + ((4 + fq) ^ (r&7))*8];      \
    }                                                                           \
  } while (0)

#define MM(MQ, NQ) do {                                                         \
    __builtin_amdgcn_s_setprio(1);                                              \
    _Pragma("unroll")                                                           \
    for (int m = 0; m < 4; m++)                                                 \
      _Pragma("unroll")                                                         \
      for (int n = 0; n < 2; n++) {                                             \
        acc[MQ][NQ][m][n] = __builtin_amdgcn_mfma_f32_16x16x32_bf16(            \
            af[m][0], bv[n][0], acc[MQ][NQ][m][n], 0, 0, 0);                    \
        acc[MQ][NQ][m][n] = __builtin_amdgcn_mfma_f32_16x16x32_bf16(            \
            af[m][1], bv[n][1], acc[MQ][NQ][m][n], 0, 0, 0);                    \
      }                                                                         \
    __builtin_amdgcn_s_setprio(0);                                              \
  } while (0)

  f32x4 zero = {0.f, 0.f, 0.f, 0.f};
  f32x4 acc[2][2][4][2];
#pragma unroll
  for (int a = 0; a < 2; a++)
#pragma unroll
    for (int b = 0; b < 2; b++)
#pragma unroll
      for (int m = 0; m < 4; m++)
#pragma unroll
        for (int n = 0; n < 2; n++) acc[a][b][m][n] = zero;

  bf16x8 af[4][2], bv[2][2];

  // prologue: tile 0 fully into buf 0
  STG(0, 0, 0, A_,   tileM, 0);
  STG(0, 0, 1, A_,   tileM, 0);
  STG(0, 1, 0, Bt_e, tileN, 0);
  STG(0, 1, 1, Bt_e, tileN, 0);
  VM0();
  BAR();

  int cb = 0;
  for (int t = 0; t < 15; ++t) {
    const int nb = cb ^ 1;
    // P1 (0,0): all 8 stage loads for tile t+1 issued here
    LOADA(cb, 0); LOADB(cb, 0);
    STG(nb, 0, 0, A_,   tileM, t + 1);
    STG(nb, 0, 1, A_,   tileM, t + 1);
    STG(nb, 1, 0, Bt_e, tileN, t + 1);
    STG(nb, 1, 1, Bt_e, tileN, t + 1);
    BAR(); MM(0, 0); BAR();
    // P2 (0,1)
    LOADB(cb, 1);
    BAR(); MM(0, 1); BAR();
    // P3 (1,1)
    LOADA(cb, 1);
    BAR(); MM(1, 1); BAR();
    // P4 (1,0): single counted drain, ~3 phases after issue
    LOADB(cb, 0);
    VM0();
    BAR(); MM(1, 0); BAR();
    cb = nb;
  }
  // last tile: no staging, no waits
  LOADA(cb, 0); LOADB(cb, 0);
  BAR(); MM(0, 0); BAR();
  LOADB(cb, 1);
  BAR(); MM(0, 1); BAR();
  LOADA(cb, 1);
  BAR(); MM(1, 1); BAR();
  LOADB(cb, 0);
  BAR(); MM(1, 0);

  // ---------------- epilogue: LDS-staged coalesced stores ----------------
  if (MODE == 0) {
    unsigned short* Ep = &LDS[0][0][0];           // 65536 u16 = 128KB
    const int reg = tileN >> 10;                  // 0=Q,1=K,2=V (uniform)
    const bool doELU = (reg < 2);
    BAR();
#pragma unroll
    for (int mq = 0; mq < 2; mq++)
#pragma unroll
      for (int nq = 0; nq < 2; nq++)
#pragma unroll
        for (int m = 0; m < 4; m++)
#pragma unroll
          for (int n = 0; n < 2; n++)
#pragma unroll
            for (int r = 0; r < 4; r++) {
              int row = mq * 128 + wmi * 64 + m * 16 + fq * 4 + r;
              int col = nq * 128 + wni * 32 + n * 16 + fr;
              float v = acc[mq][nq][m][n][r];
              if (doELU) v = v > 0.f ? v : (expf(v) - 1.f);
              Ep[row * 256 + (col ^ ((row & 7) << 3))] = f2b(v);
            }
    BAR();
    unsigned short* outp = (unsigned short*)out + (size_t)reg * M_ * H_;
    const int lcbase = tileN & 1023;
#pragma unroll
    for (int it = 0; it < 16; it++) {
      int g = it * 512 + tid;          // 8192 chunks of 16B
      int row = g >> 5, col = (g & 31) * 8;
      bf16x8 val = *(const bf16x8*)&Ep[row * 256 + (col ^ ((row & 7) << 3))];
      *(bf16x8*)&outp[(size_t)(tileM + row) * H_ + lcbase + col] = val;
    }
  } else {
    float* Ef = (float*)&LDS[0][0][0];            // 32768 f32 = 128KB
#pragma unroll
    for (int mq = 0; mq < 2; mq++) {
      BAR();
#pragma unroll
      for (int nq = 0; nq < 2; nq++)
#pragma unroll
        for (int m = 0; m < 4; m++)
#pragma unroll
          for (int n = 0; n < 2; n++)
#pragma unroll
            for (int r = 0; r < 4; r++) {
              int row = wmi * 64 + m * 16 + fq * 4 + r;    // 0..127
              int col = nq * 128 + wni * 32 + n * 16 + fr;
              Ef[row * 256 + (col ^ ((row & 7) << 2))] = acc[mq][nq][m][n][r];
            }
      BAR();
#pragma unroll
      for (int it = 0; it < 16; it++) {
        int g = it * 512 + tid;        // 8192 chunks of 16B
        int row = g >> 6, c = (g & 63) * 4;
        f32x4 val = *(const f32x4*)&Ef[row * 256 + (c ^ ((row & 7) << 2))];
        *(f32x4*)&((float*)out)[(size_t)(tileM + mq * 128 + row) * H_ + tileN + c] = val;
      }
    }
  }
#undef MM
#undef LOADB
#undef LOADA
#undef STG
}

// ---------------------------------------------------------------- stage 2: KV partials
// kvp[bh*8+ch][d][e] = sum_{s in 512-chunk} K[b,s,h,d] * V[b,s,h,e]
__global__ __launch_bounds__(256) void kv_partial(
    const unsigned short* __restrict__ Kb,
    const unsigned short* __restrict__ Vb,
    float* __restrict__ kvp) {
  __shared__ __align__(16) unsigned short kt[32 * 64];
  __shared__ __align__(16) unsigned short vt[32 * 64];
  const int bh = blockIdx.x >> 3;
  const int ch = blockIdx.x & 7;
  const int b  = bh >> 4, h = bh & 15;
  const int t  = threadIdx.x;
  const int rr = t >> 3;
  const int cc = (t & 7) * 8;
  const int d0 = (t >> 4) * 4;
  const int e0 = (t & 15) * 4;

  float acc[4][4] = {};
  for (int s0 = ch * 512; s0 < ch * 512 + 512; s0 += 32) {
    size_t g = (size_t)(b * S_ + s0 + rr) * H_ + h * 64 + cc;
    *reinterpret_cast<uint4*>(&kt[rr * 64 + cc]) = *reinterpret_cast<const uint4*>(Kb + g);
    *reinterpret_cast<uint4*>(&vt[rr * 64 + cc]) = *reinterpret_cast<const uint4*>(Vb + g);
    __syncthreads();
#pragma unroll 4
    for (int ss = 0; ss < 32; ss++) {
      ushort4 k4 = *reinterpret_cast<const ushort4*>(&kt[ss * 64 + d0]);
      ushort4 v4 = *reinterpret_cast<const ushort4*>(&vt[ss * 64 + e0]);
      float kf[4] = {b2f(k4.x), b2f(k4.y), b2f(k4.z), b2f(k4.w)};
      float vf[4] = {b2f(v4.x), b2f(v4.y), b2f(v4.z), b2f(v4.w)};
#pragma unroll
      for (int i = 0; i < 4; i++)
#pragma unroll
        for (int j = 0; j < 4; j++) acc[i][j] += kf[i] * vf[j];
    }
    __syncthreads();
  }
  float* outp = kvp + (size_t)blockIdx.x * 4096;
#pragma unroll
  for (int i = 0; i < 4; i++)
#pragma unroll
    for (int j = 0; j < 4; j++) outp[(d0 + i) * 64 + e0 + j] = acc[i][j];
}

// reduce 8 partials -> KV[bh][d][e] bf16 (row-major d)
__global__ __launch_bounds__(256) void kv_reduce(
    const float* __restrict__ kvp, unsigned short* __restrict__ KVb) {
  const int bh = blockIdx.x;
#pragma unroll
  for (int i = 0; i < 16; i++) {
    int idx = threadIdx.x + i * 256;
    float s = 0.f;
#pragma unroll
    for (int ch = 0; ch < 8; ch++) s += kvp[(size_t)(bh * 8 + ch) * 4096 + idx];
    KVb[(size_t)bh * 4096 + idx] = f2b(s);
  }
}

// ---------------------------------------------------------------- merged weight
// MbT[b][n][h*64+d] = sum_e KV[b,h][d][e] * Wo[n][h*64+e]   (Bt layout for final GEMM)
__global__ __launch_bounds__(256) void merge_m(
    const unsigned short* __restrict__ KVb,
    const unsigned short* __restrict__ Wob,
    unsigned short* __restrict__ MbT) {
  const int bh = blockIdx.x >> 2;
  const int nc = blockIdx.x & 3;
  const int b  = bh >> 4, h = bh & 15;
  const int lane = threadIdx.x & 63, wv = threadIdx.x >> 6;
  const int fr = lane & 15, fq = lane >> 4;
  const int ncb = nc * 256 + wv * 64;

  f32x4 zero = {0.f, 0.f, 0.f, 0.f};
  f32x4 acc[4][4];
#pragma unroll
  for (int i = 0; i < 4; i++)
#pragma unroll
    for (int j = 0; j < 4; j++) acc[i][j] = zero;

#pragma unroll
  for (int kk = 0; kk < 2; kk++) {
    bf16x8 af[4], bvv[4];
#pragma unroll
    for (int i = 0; i < 4; i++)
      af[i] = *(const bf16x8*)&KVb[(size_t)bh * 4096 + (i * 16 + fr) * 64 + kk * 32 + fq * 8];
#pragma unroll
    for (int j = 0; j < 4; j++)
      bvv[j] = *(const bf16x8*)&Wob[(size_t)(ncb + j * 16 + fr) * 1024 + h * 64 + kk * 32 + fq * 8];
#pragma unroll
    for (int i = 0; i < 4; i++)
#pragma unroll
      for (int j = 0; j < 4; j++)
        acc[i][j] = __builtin_amdgcn_mfma_f32_16x16x32_bf16(af[i], bvv[j], acc[i][j], 0, 0, 0);
  }
#pragma unroll
  for (int i = 0; i < 4; i++)
#pragma unroll
    for (int j = 0; j < 4; j++)
#pragma unroll
      for (int r = 0; r < 4; r++) {
        int n = ncb + j * 16 + fr;
        int k = h * 64 + i * 16 + fq * 4 + r;
        MbT[((size_t)b << 20) + (size_t)n * 1024 + k] = f2b(acc[i][j][r]);
      }
}

// ---------------------------------------------------------------- launch
extern "C" void kernel_launch(void* const* d_in, const int* in_sizes, int n_in,
                              void* d_out, int out_size, void* d_ws, size_t ws_size,
                              hipStream_t stream) {
  (void)in_sizes; (void)n_in; (void)out_size; (void)ws_size;
  const float* X  = (const float*)d_in[0];
  const float* Wq = (const float*)d_in[1];
  const float* Wk = (const float*)d_in[2];
  const float* Wv = (const float*)d_in[3];
  const float* Wo = (const float*)d_in[4];

  char*  ws  = (char*)d_ws;
  size_t off = 0;
  auto alloc = [&](size_t bytes) -> char* {
    char* p = ws + off;
    off += (bytes + 255) & ~(size_t)255;
    return p;
  };
  unsigned short* Xb   = (unsigned short*)alloc((size_t)M_ * H_ * 2);
  unsigned short* Wcat = (unsigned short*)alloc((size_t)4 * H_ * H_ * 2);  // Wq|Wk|Wv|Wo
  unsigned short* QKVb = (unsigned short*)alloc((size_t)3 * M_ * H_ * 2);  // Q|K|V
  float*          kvp  = (float*)alloc((size_t)64 * 8 * 4096 * 4);
  unsigned short* KVb  = (unsigned short*)alloc((size_t)64 * 4096 * 2);
  unsigned short* MbT  = (unsigned short*)alloc((size_t)4 * H_ * H_ * 2);

  unsigned short* Qb = QKVb;
  unsigned short* Kb = QKVb + (size_t)M_ * H_;
  unsigned short* Vb = QKVb + (size_t)2 * M_ * H_;
  unsigned short* Wob = Wcat + (size_t)3 * H_ * H_;

  cast_f32_bf16<<<(M_ * H_) / 1024, 256, 0, stream>>>(X, Xb, (M_ * H_) / 4);
  cast_w4<<<(4 * H_ * H_) / 1024, 256, 0, stream>>>(Wq, Wk, Wv, Wo, Wcat);

  gemm256<0><<<768, 512, 0, stream>>>(Xb, Wcat, QKVb);   // Q,K,V (ELU on Q,K)

  kv_partial<<<512, 256, 0, stream>>>(Kb, Vb, kvp);
  kv_reduce<<<64, 256, 0, stream>>>(kvp, KVb);
  merge_m<<<256, 256, 0, stream>>>(KVb, Wob, MbT);

  gemm256<1><<<256, 512, 0, stream>>>(Qb, MbT, (float*)d_out);  // Y = Q @ M[b]^T
}

// Round 5
// 259.556 us; speedup vs baseline: 1.0638x; 1.0468x over previous
//
#include <hip/hip_runtime.h>
#include <cstdint>
#include <cstddef>

#define B_  4
#define S_  4096
#define H_  1024
#define NH_ 16
#define M_  (B_*S_)   // 16384 rows

typedef __bf16 bf16x8 __attribute__((ext_vector_type(8)));
typedef float  f32x4  __attribute__((ext_vector_type(4)));

__device__ __forceinline__ unsigned short f2b(float f) {
  union { float f; unsigned u; } v; v.f = f;
  unsigned r = v.u + 0x7FFFu + ((v.u >> 16) & 1u);
  return (unsigned short)(r >> 16);
}
__device__ __forceinline__ float b2f(unsigned short u) {
  union { unsigned u; float f; } v; v.u = ((unsigned)u) << 16;
  return v.f;
}

#define GLD16(g, l) __builtin_amdgcn_global_load_lds( \
    (const __attribute__((address_space(1))) void*)(g), \
    (__attribute__((address_space(3))) void*)(l), 16, 0, 0)

#define VM0()  asm volatile("s_waitcnt vmcnt(0)" ::: "memory")
#define VM2()  asm volatile("s_waitcnt vmcnt(2)" ::: "memory")
#define VM4()  asm volatile("s_waitcnt vmcnt(4)" ::: "memory")
#define BAR()  do { asm volatile("" ::: "memory"); __builtin_amdgcn_s_barrier(); \
                    asm volatile("" ::: "memory"); } while (0)

// ---------------------------------------------------------------- casts
__global__ void cast_f32_bf16(const float* __restrict__ src,
                              unsigned short* __restrict__ dst, int n4) {
  int i = blockIdx.x * blockDim.x + threadIdx.x;
  if (i >= n4) return;
  float4 f = reinterpret_cast<const float4*>(src)[i];
  ushort4 o;
  o.x = f2b(f.x); o.y = f2b(f.y); o.z = f2b(f.z); o.w = f2b(f.w);
  reinterpret_cast<ushort4*>(dst)[i] = o;
}

// 4 weights (1M elems each) -> one concatenated bf16 buffer [4][1024][1024]
__global__ void cast_w4(const float* __restrict__ w0, const float* __restrict__ w1,
                        const float* __restrict__ w2, const float* __restrict__ w3,
                        unsigned short* __restrict__ dst) {
  int i = blockIdx.x * blockDim.x + threadIdx.x;      // float4 index, 1M total
  int w = i >> 18, j = i & 0x3FFFF;
  const float* src = (w == 0) ? w0 : (w == 1) ? w1 : (w == 2) ? w2 : w3;
  float4 f = reinterpret_cast<const float4*>(src)[j];
  ushort4 o;
  o.x = f2b(f.x); o.y = f2b(f.y); o.z = f2b(f.z); o.w = f2b(f.w);
  reinterpret_cast<ushort4*>(dst)[i] = o;
}

// ---------------------------------------------------------------- 256x256 GEMM
// C[M,N] = A[M,1024] * Bt[N,1024]^T, BK=64, 512 thr = 8 waves (2M x 4N).
// Quadrant phases (0,0)->(0,1)->(1,1)->(1,0); each reloads only the changed
// operand. Counted-vmcnt staging (T4): one half-tile (2 gload_lds) per phase,
// issue order A0@P1, B0@P2, B1@P3, A1@P4 into buf^1. Certification ledger:
//   end-P1/P2/P4: vmcnt(4)  (the 2 younger half-tiles stay in flight)
//   end-P3: none.  Never vmcnt(0) in the main loop; min slack 2 phases.
// LDS swizzle: 16B-chunk index ^= (row & 7) on both stage-source and reads.
// Epilogue: regs -> XOR-swizzled LDS -> b128 readback -> coalesced dwordx4.
// MODE 0: N=3072, bf16 out routed to Q/K/V with ELU on Q,K.
// MODE 1: N=1024, Bt is per-batch [4][1024][1024], f32 out.
template<int MODE>
__global__ __launch_bounds__(512, 2) void gemm256(
    const unsigned short* __restrict__ A_,
    const unsigned short* __restrict__ Bt_,
    void* __restrict__ out) {
  __shared__ __align__(16) unsigned short LDS[2][2][16384];  // [dbuf][A|B][256*64]

  const int NTN = (MODE == 0) ? 12 : 4;
  const int nx  = gridDim.x >> 3;
  const int b2  = (blockIdx.x & 7) * nx + (blockIdx.x >> 3);  // XCD swizzle (grid%8==0)
  const int tileM = (b2 / NTN) << 8;
  const int tileN = (b2 % NTN) << 8;

  const unsigned short* Bt_e =
      (MODE == 1) ? (Bt_ + ((size_t)(tileM >> 12) << 20)) : Bt_;

  const int tid  = threadIdx.x;
  const int lane = tid & 63, wv = tid >> 6;
  const int wmi  = wv >> 2;     // 0..1
  const int wni  = wv & 3;      // 0..3
  const int fr   = lane & 15, fq = lane >> 4;

  // staging source (pre-swizzled): instr i in {0,1}: chunk c = i*512 + tid
  const int sr0 = tid >> 3,          sc0 = (tid & 7) ^ (sr0 & 7);
  const int sr1 = (tid + 512) >> 3,  sc1 = (tid & 7) ^ (sr1 & 7);

#define STG(NB, ARR, HM, SRC, RB, TT) do {                                      \
    GLD16((SRC) + (size_t)((RB) + (HM)*128 + sr0) * 1024 + (TT)*64 + sc0*8,     \
          &LDS[NB][ARR][(HM)*8192 + wv*512]);                                   \
    GLD16((SRC) + (size_t)((RB) + (HM)*128 + sr1) * 1024 + (TT)*64 + sc1*8,     \
          &LDS[NB][ARR][(HM)*8192 + 4096 + wv*512]);                            \
  } while (0)

#define LOADA(CB, MQ) do {                                                      \
    _Pragma("unroll")                                                           \
    for (int m = 0; m < 4; m++) {                                               \
      int r = (MQ)*128 + wmi*64 + m*16 + fr;                                    \
      af[m][0] = *(const bf16x8*)&LDS[CB][0][r*64 + ((fq    ) ^ (r&7))*8];      \
      af[m][1] = *(const bf16x8*)&LDS[CB][0][r*64 + ((4 + fq) ^ (r&7))*8];      \
    }                                                                           \
  } while (0)

#define LOADB(CB, NQ) do {                                                      \
    _Pragma("unroll")                                                           \
    for (int n = 0; n < 2; n++) {                                               \
      int r = (NQ)*128 + wni*32 + n*16 + fr;                                    \
      bv[n][0] = *(const bf16x8*)&LDS[CB][1][r*64 + ((fq    ) ^ (r&7))*8];      \
      bv[n][1] = *(const bf16x8*)&LDS[CB][1][r*64 + ((4 + fq) ^ (r&7))*8];      \
    }                                                                           \
  } while (0)

#define MM(MQ, NQ) do {                                                         \
    __builtin_amdgcn_s_setprio(1);                                              \
    _Pragma("unroll")                                                           \
    for (int m = 0; m < 4; m++)                                                 \
      _Pragma("unroll")                                                         \
      for (int n = 0; n < 2; n++) {                                             \
        acc[MQ][NQ][m][n] = __builtin_amdgcn_mfma_f32_16x16x32_bf16(            \
            af[m][0], bv[n][0], acc[MQ][NQ][m][n], 0, 0, 0);                    \
        acc[MQ][NQ][m][n] = __builtin_amdgcn_mfma_f32_16x16x32_bf16(            \
            af[m][1], bv[n][1], acc[MQ][NQ][m][n], 0, 0, 0);                    \
      }                                                                         \
    __builtin_amdgcn_s_setprio(0);                                              \
  } while (0)

  f32x4 zero = {0.f, 0.f, 0.f, 0.f};
  f32x4 acc[2][2][4][2];
#pragma unroll
  for (int a = 0; a < 2; a++)
#pragma unroll
    for (int b = 0; b < 2; b++)
#pragma unroll
      for (int m = 0; m < 4; m++)
#pragma unroll
        for (int n = 0; n < 2; n++) acc[a][b][m][n] = zero;

  bf16x8 af[4][2], bv[2][2];

  // prologue: tile 0 fully into buf 0
  STG(0, 0, 0, A_,   tileM, 0);
  STG(0, 0, 1, A_,   tileM, 0);
  STG(0, 1, 0, Bt_e, tileN, 0);
  STG(0, 1, 1, Bt_e, tileN, 0);
  VM0();
  BAR();

  int cb = 0;
  for (int t = 0; t < 15; ++t) {
    const int nb = cb ^ 1;
    // P1 (0,0)  | stage A0(t+1)
    LOADA(cb, 0); LOADB(cb, 0);
    STG(nb, 0, 0, A_,   tileM, t + 1);
    BAR(); MM(0, 0); VM4(); BAR();
    // P2 (0,1)  | stage B0(t+1)
    LOADB(cb, 1);
    STG(nb, 1, 0, Bt_e, tileN, t + 1);
    BAR(); MM(0, 1); VM4(); BAR();
    // P3 (1,1)  | stage B1(t+1)
    LOADA(cb, 1);
    STG(nb, 1, 1, Bt_e, tileN, t + 1);
    BAR(); MM(1, 1); BAR();
    // P4 (1,0)  | stage A1(t+1)
    LOADB(cb, 0);
    STG(nb, 0, 1, A_,   tileM, t + 1);
    BAR(); MM(1, 0); VM4(); BAR();
    cb = nb;
  }
  // last tile: no staging; drain progressively
  LOADA(cb, 0); LOADB(cb, 0);
  BAR(); MM(0, 0); VM2(); BAR();
  LOADB(cb, 1);
  BAR(); MM(0, 1); VM0(); BAR();
  LOADA(cb, 1);
  BAR(); MM(1, 1); BAR();
  LOADB(cb, 0);
  BAR(); MM(1, 0);

  // ---------------- epilogue: LDS-staged coalesced stores ----------------
  if (MODE == 0) {
    unsigned short* Ep = &LDS[0][0][0];           // 65536 u16 = 128KB
    const int reg = tileN >> 10;                  // 0=Q,1=K,2=V (uniform)
    const bool doELU = (reg < 2);
    BAR();
#pragma unroll
    for (int mq = 0; mq < 2; mq++)
#pragma unroll
      for (int nq = 0; nq < 2; nq++)
#pragma unroll
        for (int m = 0; m < 4; m++)
#pragma unroll
          for (int n = 0; n < 2; n++)
#pragma unroll
            for (int r = 0; r < 4; r++) {
              int row = mq * 128 + wmi * 64 + m * 16 + fq * 4 + r;
              int col = nq * 128 + wni * 32 + n * 16 + fr;
              float v = acc[mq][nq][m][n][r];
              if (doELU) v = v > 0.f ? v : (expf(v) - 1.f);
              Ep[row * 256 + (col ^ ((row & 7) << 3))] = f2b(v);
            }
    BAR();
    unsigned short* outp = (unsigned short*)out + (size_t)reg * M_ * H_;
    const int lcbase = tileN & 1023;
#pragma unroll
    for (int it = 0; it < 16; it++) {
      int g = it * 512 + tid;          // 8192 chunks of 16B
      int row = g >> 5, col = (g & 31) * 8;
      bf16x8 val = *(const bf16x8*)&Ep[row * 256 + (col ^ ((row & 7) << 3))];
      *(bf16x8*)&outp[(size_t)(tileM + row) * H_ + lcbase + col] = val;
    }
  } else {
    float* Ef = (float*)&LDS[0][0][0];            // 32768 f32 = 128KB
#pragma unroll
    for (int mq = 0; mq < 2; mq++) {
      BAR();
#pragma unroll
      for (int nq = 0; nq < 2; nq++)
#pragma unroll
        for (int m = 0; m < 4; m++)
#pragma unroll
          for (int n = 0; n < 2; n++)
#pragma unroll
            for (int r = 0; r < 4; r++) {
              int row = wmi * 64 + m * 16 + fq * 4 + r;    // 0..127
              int col = nq * 128 + wni * 32 + n * 16 + fr;
              Ef[row * 256 + (col ^ ((row & 7) << 2))] = acc[mq][nq][m][n][r];
            }
      BAR();
#pragma unroll
      for (int it = 0; it < 16; it++) {
        int g = it * 512 + tid;        // 8192 chunks of 16B
        int row = g >> 6, c = (g & 63) * 4;
        f32x4 val = *(const f32x4*)&Ef[row * 256 + (c ^ ((row & 7) << 2))];
        *(f32x4*)&((float*)out)[(size_t)(tileM + mq * 128 + row) * H_ + tileN + c] = val;
      }
    }
  }
#undef MM
#undef LOADB
#undef LOADA
#undef STG
}

// ---------------------------------------------------------------- stage 2: KV partials
// kvp[bh*8+ch][d][e] = sum_{s in 512-chunk} K[b,s,h,d] * V[b,s,h,e]
__global__ __launch_bounds__(256) void kv_partial(
    const unsigned short* __restrict__ Kb,
    const unsigned short* __restrict__ Vb,
    float* __restrict__ kvp) {
  __shared__ __align__(16) unsigned short kt[32 * 64];
  __shared__ __align__(16) unsigned short vt[32 * 64];
  const int bh = blockIdx.x >> 3;
  const int ch = blockIdx.x & 7;
  const int b  = bh >> 4, h = bh & 15;
  const int t  = threadIdx.x;
  const int rr = t >> 3;
  const int cc = (t & 7) * 8;
  const int d0 = (t >> 4) * 4;
  const int e0 = (t & 15) * 4;

  float acc[4][4] = {};
  for (int s0 = ch * 512; s0 < ch * 512 + 512; s0 += 32) {
    size_t g = (size_t)(b * S_ + s0 + rr) * H_ + h * 64 + cc;
    *reinterpret_cast<uint4*>(&kt[rr * 64 + cc]) = *reinterpret_cast<const uint4*>(Kb + g);
    *reinterpret_cast<uint4*>(&vt[rr * 64 + cc]) = *reinterpret_cast<const uint4*>(Vb + g);
    __syncthreads();
#pragma unroll 4
    for (int ss = 0; ss < 32; ss++) {
      ushort4 k4 = *reinterpret_cast<const ushort4*>(&kt[ss * 64 + d0]);
      ushort4 v4 = *reinterpret_cast<const ushort4*>(&vt[ss * 64 + e0]);
      float kf[4] = {b2f(k4.x), b2f(k4.y), b2f(k4.z), b2f(k4.w)};
      float vf[4] = {b2f(v4.x), b2f(v4.y), b2f(v4.z), b2f(v4.w)};
#pragma unroll
      for (int i = 0; i < 4; i++)
#pragma unroll
        for (int j = 0; j < 4; j++) acc[i][j] += kf[i] * vf[j];
    }
    __syncthreads();
  }
  float* outp = kvp + (size_t)blockIdx.x * 4096;
#pragma unroll
  for (int i = 0; i < 4; i++)
#pragma unroll
    for (int j = 0; j < 4; j++) outp[(d0 + i) * 64 + e0 + j] = acc[i][j];
}

// reduce 8 partials -> KV[bh][d][e] bf16 (row-major d)
__global__ __launch_bounds__(256) void kv_reduce(
    const float* __restrict__ kvp, unsigned short* __restrict__ KVb) {
  const int bh = blockIdx.x;
#pragma unroll
  for (int i = 0; i < 16; i++) {
    int idx = threadIdx.x + i * 256;
    float s = 0.f;
#pragma unroll
    for (int ch = 0; ch < 8; ch++) s += kvp[(size_t)(bh * 8 + ch) * 4096 + idx];
    KVb[(size_t)bh * 4096 + idx] = f2b(s);
  }
}

// ---------------------------------------------------------------- merged weight
// MbT[b][n][h*64+d] = sum_e KV[b,h][d][e] * Wo[n][h*64+e]   (Bt layout for final GEMM)
__global__ __launch_bounds__(256) void merge_m(
    const unsigned short* __restrict__ KVb,
    const unsigned short* __restrict__ Wob,
    unsigned short* __restrict__ MbT) {
  const int bh = blockIdx.x >> 2;
  const int nc = blockIdx.x & 3;
  const int b  = bh >> 4, h = bh & 15;
  const int lane = threadIdx.x & 63, wv = threadIdx.x >> 6;
  const int fr = lane & 15, fq = lane >> 4;
  const int ncb = nc * 256 + wv * 64;

  f32x4 zero = {0.f, 0.f, 0.f, 0.f};
  f32x4 acc[4][4];
#pragma unroll
  for (int i = 0; i < 4; i++)
#pragma unroll
    for (int j = 0; j < 4; j++) acc[i][j] = zero;

#pragma unroll
  for (int kk = 0; kk < 2; kk++) {
    bf16x8 af[4], bvv[4];
#pragma unroll
    for (int i = 0; i < 4; i++)
      af[i] = *(const bf16x8*)&KVb[(size_t)bh * 4096 + (i * 16 + fr) * 64 + kk * 32 + fq * 8];
#pragma unroll
    for (int j = 0; j < 4; j++)
      bvv[j] = *(const bf16x8*)&Wob[(size_t)(ncb + j * 16 + fr) * 1024 + h * 64 + kk * 32 + fq * 8];
#pragma unroll
    for (int i = 0; i < 4; i++)
#pragma unroll
      for (int j = 0; j < 4; j++)
        acc[i][j] = __builtin_amdgcn_mfma_f32_16x16x32_bf16(af[i], bvv[j], acc[i][j], 0, 0, 0);
  }
#pragma unroll
  for (int i = 0; i < 4; i++)
#pragma unroll
    for (int j = 0; j < 4; j++)
#pragma unroll
      for (int r = 0; r < 4; r++) {
        int n = ncb + j * 16 + fr;
        int k = h * 64 + i * 16 + fq * 4 + r;
        MbT[((size_t)b << 20) + (size_t)n * 1024 + k] = f2b(acc[i][j][r]);
      }
}

// ---------------------------------------------------------------- launch
extern "C" void kernel_launch(void* const* d_in, const int* in_sizes, int n_in,
                              void* d_out, int out_size, void* d_ws, size_t ws_size,
                              hipStream_t stream) {
  (void)in_sizes; (void)n_in; (void)out_size; (void)ws_size;
  const float* X  = (const float*)d_in[0];
  const float* Wq = (const float*)d_in[1];
  const float* Wk = (const float*)d_in[2];
  const float* Wv = (const float*)d_in[3];
  const float* Wo = (const float*)d_in[4];

  char*  ws  = (char*)d_ws;
  size_t off = 0;
  auto alloc = [&](size_t bytes) -> char* {
    char* p = ws + off;
    off += (bytes + 255) & ~(size_t)255;
    return p;
  };
  unsigned short* Xb   = (unsigned short*)alloc((size_t)M_ * H_ * 2);
  unsigned short* Wcat = (unsigned short*)alloc((size_t)4 * H_ * H_ * 2);  // Wq|Wk|Wv|Wo
  unsigned short* QKVb = (unsigned short*)alloc((size_t)3 * M_ * H_ * 2);  // Q|K|V
  float*          kvp  = (float*)alloc((size_t)64 * 8 * 4096 * 4);
  unsigned short* KVb  = (unsigned short*)alloc((size_t)64 * 4096 * 2);
  unsigned short* MbT  = (unsigned short*)alloc((size_t)4 * H_ * H_ * 2);

  unsigned short* Qb = QKVb;
  unsigned short* Kb = QKVb + (size_t)M_ * H_;
  unsigned short* Vb = QKVb + (size_t)2 * M_ * H_;
  unsigned short* Wob = Wcat + (size_t)3 * H_ * H_;

  cast_f32_bf16<<<(M_ * H_) / 1024, 256, 0, stream>>>(X, Xb, (M_ * H_) / 4);
  cast_w4<<<(4 * H_ * H_) / 1024, 256, 0, stream>>>(Wq, Wk, Wv, Wo, Wcat);

  gemm256<0><<<768, 512, 0, stream>>>(Xb, Wcat, QKVb);   // Q,K,V (ELU on Q,K)

  kv_partial<<<512, 256, 0, stream>>>(Kb, Vb, kvp);
  kv_reduce<<<64, 256, 0, stream>>>(kvp, KVb);
  merge_m<<<256, 256, 0, stream>>>(KVb, Wob, MbT);

  gemm256<1><<<256, 512, 0, stream>>>(Qb, MbT, (float*)d_out);  // Y = Q @ M[b]^T
}